// Round 1
// baseline (354.733 us; speedup 1.0000x reference)
//
#include <hip/hip_runtime.h>
#include <math.h>

#define T_TOK 4096
#define DM 1024
#define HID 4096
#define NEXP 8

typedef unsigned short u16;
typedef __attribute__((ext_vector_type(8))) short short8;
typedef __attribute__((ext_vector_type(4))) float f32x4;

__device__ __forceinline__ u16 f2bf(float f){
  unsigned u = __float_as_uint(f);
  u += 0x7FFF + ((u >> 16) & 1);
  return (u16)(u >> 16);
}
__device__ __forceinline__ float bf2f(u16 b){
  return __uint_as_float(((unsigned)b) << 16);
}

// ---- workspace layout (byte offsets) ----
#define GATE_OFF   0u          // float[4096]
#define CNT_OFF    16384u      // int[8]
#define LIST_OFF   16512u      // int[8][4096]
#define PROBS_OFF  147584u     // float[4096][8]
#define XB_OFF     278656u     // bf16[4096][1024]
#define H_OFF      8667264u    // bf16[4096][4096]
// total needed: 42,221,696 bytes (~40.3 MB)

__global__ void zero_cnt_kernel(int* cnt){
  if (threadIdx.x < NEXP) cnt[threadIdx.x] = 0;
}

// one wave per token: gating + routing + x->bf16 conversion
__global__ __launch_bounds__(256) void gate_kernel(
    const float* __restrict__ x, const float* __restrict__ gw,
    float* __restrict__ gateo, int* __restrict__ cnt, int* __restrict__ list,
    float* __restrict__ probs, u16* __restrict__ xb)
{
  int tid = threadIdx.x;
  int lane = tid & 63;
  int w = tid >> 6;
  int t = blockIdx.x * 4 + w;

  const float4* x4 = (const float4*)(x + (size_t)t * DM);
  const float4* g4 = (const float4*)gw;

  float acc[8] = {0,0,0,0,0,0,0,0};
  #pragma unroll
  for (int i = 0; i < 4; i++){
    int p = i * 64 + lane;           // float4 index within row (0..255)
    float4 xv = x4[p];
    ushort4 pk;
    pk.x = f2bf(xv.x); pk.y = f2bf(xv.y); pk.z = f2bf(xv.z); pk.w = f2bf(xv.w);
    *(ushort4*)&xb[(size_t)t * DM + (size_t)p * 4] = pk;
    #pragma unroll
    for (int e = 0; e < NEXP; e++){
      float4 gv = g4[e * 256 + p];
      acc[e] += xv.x * gv.x + xv.y * gv.y + xv.z * gv.z + xv.w * gv.w;
    }
  }
  #pragma unroll
  for (int e = 0; e < NEXP; e++){
    #pragma unroll
    for (int off = 32; off; off >>= 1)
      acc[e] += __shfl_xor(acc[e], off);
  }
  if (lane == 0){
    float mx = acc[0];
    #pragma unroll
    for (int e = 1; e < NEXP; e++) mx = fmaxf(mx, acc[e]);
    float p[8]; float s = 0.f;
    #pragma unroll
    for (int e = 0; e < NEXP; e++){ p[e] = expf(acc[e] - mx); s += p[e]; }
    float inv = 1.f / s;
    int be = 0; float bp = p[0];
    #pragma unroll
    for (int e = 1; e < NEXP; e++){ if (p[e] > bp){ bp = p[e]; be = e; } }
    #pragma unroll
    for (int e = 0; e < NEXP; e++) probs[(size_t)t * 8 + e] = p[e] * inv;
    gateo[t] = bp * inv;
    int pos = atomicAdd(&cnt[be], 1);
    list[be * T_TOK + pos] = t;
  }
}

// deterministic aux-loss reduction, one block
__global__ __launch_bounds__(256) void aux_kernel(
    const float* __restrict__ probs, const int* __restrict__ cnt,
    float* __restrict__ aux_out)
{
  __shared__ float sm[256 * 8];
  int tid = threadIdx.x;
  float s[8] = {0,0,0,0,0,0,0,0};
  for (int i = 0; i < 16; i++){
    int t = i * 256 + tid;
    #pragma unroll
    for (int e = 0; e < 8; e++) s[e] += probs[(size_t)t * 8 + e];
  }
  #pragma unroll
  for (int e = 0; e < 8; e++) sm[tid * 8 + e] = s[e];
  __syncthreads();
  for (int st = 128; st; st >>= 1){
    if (tid < st){
      #pragma unroll
      for (int e = 0; e < 8; e++) sm[tid * 8 + e] += sm[(tid + st) * 8 + e];
    }
    __syncthreads();
  }
  if (tid == 0){
    float a = 0.f;
    #pragma unroll
    for (int e = 0; e < 8; e++){
      float f = (float)cnt[e] / (float)T_TOK;
      float P = sm[e] / (float)T_TOK;
      a += f * P;
    }
    aux_out[0] = 0.01f * (float)NEXP * a;
  }
}

// grouped GEMM: C[tok][n] = sum_k A[tok][k] * B[e][n][k]  (+bias, epilogue)
// PHASE2=false: A=xb, B=w1, out=h (gelu, bf16)
// PHASE2=true : A=h,  B=w2, out=y=gate*(acc+b2) scatter to d_out (fp32)
template<int KT, int NTOT, bool PHASE2>
__global__ __launch_bounds__(256, 2) void ffn_gemm(
    const u16*  __restrict__ Aall,   // [4096][KT] bf16
    const float* __restrict__ Ball,  // [E][NTOT][KT] fp32
    const float* __restrict__ bias,  // [E][NTOT]
    const int*  __restrict__ cnt,
    const int*  __restrict__ list,   // [E][4096]
    const float* __restrict__ gate,  // [4096]
    u16*  __restrict__ hOut,         // phase1 out
    float* __restrict__ yOut)        // phase2 out
{
  constexpr int NT = NTOT / 128;
  int bid = blockIdx.x;
  int e  = bid / (32 * NT);
  int r  = bid % (32 * NT);
  int mt = r / NT, nt = r % NT;
  int ne = cnt[e];
  int m0 = mt * 128;
  if (m0 >= ne) return;
  const int*   lst = list + e * T_TOK;
  const float* B   = Ball + (size_t)e * NTOT * KT;
  const float* bi  = bias + (size_t)e * NTOT;
  int n0 = nt * 128;

  __shared__ u16 As[128 * 64];
  __shared__ u16 Bs[128 * 64];

  int tid  = threadIdx.x;
  int lane = tid & 63;
  int w    = tid >> 6;
  int wr = (w >> 1) * 64, wc = (w & 1) * 64;
  int fr = lane & 15, fq = lane >> 4;

  // staging ownership: idx = i*256+tid -> row = idx>>3, chunk = idx&7
  const u16*  aSrc[4]; int dstA[4];
  const float* bSrc[4]; int dstB[4];
  #pragma unroll
  for (int i = 0; i < 4; i++){
    int idx = i * 256 + tid;
    int row = idx >> 3, ch = idx & 7;
    int g = ch ^ (row & 7);                 // logical 16B chunk to fetch
    int mrow = m0 + row; if (mrow > ne - 1) mrow = ne - 1;
    int tok = lst[mrow];
    aSrc[i] = Aall + (size_t)tok * KT + g * 8;
    dstA[i] = row * 64 + ch * 8;
    bSrc[i] = B + (size_t)(n0 + row) * KT + g * 8;
    dstB[i] = row * 64 + ch * 8;
  }

  f32x4 acc[4][4];
  #pragma unroll
  for (int m = 0; m < 4; m++)
    #pragma unroll
    for (int n = 0; n < 4; n++)
      acc[m][n] = (f32x4){0.f, 0.f, 0.f, 0.f};

  for (int ks = 0; ks < KT / 64; ++ks){
    if (ks) __syncthreads();
    int ko = ks * 64;
    #pragma unroll
    for (int i = 0; i < 4; i++){
      *(uint4*)&As[dstA[i]] = *(const uint4*)(aSrc[i] + ko);
    }
    #pragma unroll
    for (int i = 0; i < 4; i++){
      const float4* s = (const float4*)(bSrc[i] + ko);
      float4 f0 = s[0], f1 = s[1];
      uint4 p;
      p.x = (unsigned)f2bf(f0.x) | ((unsigned)f2bf(f0.y) << 16);
      p.y = (unsigned)f2bf(f0.z) | ((unsigned)f2bf(f0.w) << 16);
      p.z = (unsigned)f2bf(f1.x) | ((unsigned)f2bf(f1.y) << 16);
      p.w = (unsigned)f2bf(f1.z) | ((unsigned)f2bf(f1.w) << 16);
      *(uint4*)&Bs[dstB[i]] = p;
    }
    __syncthreads();
    #pragma unroll
    for (int kc = 0; kc < 2; kc++){
      short8 a[4], b[4];
      #pragma unroll
      for (int m = 0; m < 4; m++){
        int row = wr + m * 16 + fr;
        int slot = (kc * 4 + fq) ^ (row & 7);
        a[m] = *(const short8*)&As[row * 64 + slot * 8];
      }
      #pragma unroll
      for (int n = 0; n < 4; n++){
        int row = wc + n * 16 + fr;
        int slot = (kc * 4 + fq) ^ (row & 7);
        b[n] = *(const short8*)&Bs[row * 64 + slot * 8];
      }
      #pragma unroll
      for (int m = 0; m < 4; m++)
        #pragma unroll
        for (int n = 0; n < 4; n++)
          acc[m][n] = __builtin_amdgcn_mfma_f32_16x16x32_bf16(a[m], b[n], acc[m][n], 0, 0, 0);
    }
  }

  // epilogue: C frag layout col = lane&15, row = (lane>>4)*4 + i
  #pragma unroll
  for (int n = 0; n < 4; n++){
    int col = n0 + wc + n * 16 + fr;
    float bv = bi[col];
    #pragma unroll
    for (int m = 0; m < 4; m++){
      int rbase = m0 + wr + m * 16 + fq * 4;
      f32x4 v = acc[m][n];
      #pragma unroll
      for (int i = 0; i < 4; i++){
        int mrow = rbase + i;
        if (mrow < ne){
          int tok = lst[mrow];
          float val = v[i] + bv;
          if (PHASE2){
            yOut[(size_t)tok * NTOT + col] = gate[tok] * val;
          } else {
            float gl = 0.5f * val * (1.0f + erff(val * 0.70710678118654752f));
            hOut[(size_t)tok * NTOT + col] = f2bf(gl);
          }
        }
      }
    }
  }
}

extern "C" void kernel_launch(void* const* d_in, const int* in_sizes, int n_in,
                              void* d_out, int out_size, void* d_ws, size_t ws_size,
                              hipStream_t stream) {
  const float* x   = (const float*)d_in[0];
  const float* gw  = (const float*)d_in[1];
  const float* w1  = (const float*)d_in[2];
  const float* b1  = (const float*)d_in[3];
  const float* w2  = (const float*)d_in[4];
  const float* b2  = (const float*)d_in[5];

  char* ws = (char*)d_ws;
  float* gateo = (float*)(ws + GATE_OFF);
  int*   cnt   = (int*)  (ws + CNT_OFF);
  int*   list  = (int*)  (ws + LIST_OFF);
  float* probs = (float*)(ws + PROBS_OFF);
  u16*   xb    = (u16*)  (ws + XB_OFF);
  u16*   h     = (u16*)  (ws + H_OFF);

  float* out = (float*)d_out;
  float* aux = out + (size_t)T_TOK * DM;

  hipLaunchKernelGGL(zero_cnt_kernel, dim3(1), dim3(64), 0, stream, cnt);
  hipLaunchKernelGGL(gate_kernel, dim3(T_TOK / 4), dim3(256), 0, stream,
                     x, gw, gateo, cnt, list, probs, xb);
  hipLaunchKernelGGL(aux_kernel, dim3(1), dim3(256), 0, stream, probs, cnt, aux);
  hipLaunchKernelGGL((ffn_gemm<DM, HID, false>), dim3(NEXP * 32 * (HID / 128)), dim3(256), 0, stream,
                     xb, w1, b1, cnt, list, gateo, h, (float*)nullptr);
  hipLaunchKernelGGL((ffn_gemm<HID, DM, true>), dim3(NEXP * 32 * (DM / 128)), dim3(256), 0, stream,
                     h, w2, b2, cnt, list, gateo, (u16*)nullptr, out);
}